// Round 4
// baseline (1367.930 us; speedup 1.0000x reference)
//
#include <hip/hip_runtime.h>
#include <cmath>

static __device__ __forceinline__ float eluf(float v) { return v > 0.f ? v : expm1f(v); }

// ---------------- stage 1: fused offset-conv + deformable conv (C=1 -> 32) ----------------
__global__ __launch_bounds__(256) void k_deform1(
    const float* __restrict__ x, const float* __restrict__ woff, const float* __restrict__ boff,
    const float* __restrict__ w1, const float* __restrict__ b1, float* __restrict__ y1)
{
  __shared__ float s_woff[81 * 28];   // rows padded to 28 for 16B alignment
  __shared__ float s_w1t[27 * 32];    // [n][o]
  __shared__ float s_boff[81];
  __shared__ float s_b1[32];
  const int tid = threadIdx.x;
  for (int i = tid; i < 81 * 28; i += 256) {
    int ch = i / 28, m = i % 28;
    s_woff[i] = (m < 27) ? woff[ch * 27 + m] : 0.f;
  }
  for (int i = tid; i < 27 * 32; i += 256) {
    int n = i >> 5, o = i & 31;
    s_w1t[i] = w1[o * 27 + n];
  }
  if (tid < 81) s_boff[tid] = boff[tid];
  if (tid < 32) s_b1[tid] = b1[tid];
  __syncthreads();

  const int gid = blockIdx.x * 256 + tid;
  const int w = gid & 63;
  const int h = (gid >> 6) % 48;
  const int d = ((gid >> 6) / 48) % 24;
  const int b = gid / (64 * 48 * 24);
  const float* __restrict__ xb = x + (size_t)b * (24 * 48 * 64);

  float xn[27];
  #pragma unroll
  for (int kd = 0; kd < 3; ++kd)
    #pragma unroll
    for (int kh = 0; kh < 3; ++kh)
      #pragma unroll
      for (int kw = 0; kw < 3; ++kw) {
        int zd = d + kd - 1, yh = h + kh - 1, xw = w + kw - 1;
        bool ok = (unsigned)zd < 24u && (unsigned)yh < 48u && (unsigned)xw < 64u;
        xn[(kd * 3 + kh) * 3 + kw] = ok ? xb[(zd * 48 + yh) * 64 + xw] : 0.f;
      }

  float acc[32];
  #pragma unroll
  for (int o = 0; o < 32; ++o) acc[o] = 0.f;

  #pragma unroll 1
  for (int n = 0; n < 27; ++n) {
    const float* wrd = &s_woff[n * 28];
    const float* wrh = &s_woff[(27 + n) * 28];
    const float* wrw = &s_woff[(54 + n) * 28];
    float ofd = s_boff[n], ofh = s_boff[27 + n], ofw = s_boff[54 + n];
    #pragma unroll
    for (int m = 0; m < 27; ++m) {
      float xv = xn[m];
      ofd += wrd[m] * xv; ofh += wrh[m] * xv; ofw += wrw[m] * xv;
    }
    const int pnd = n / 9 - 1, pnh = (n / 3) % 3 - 1, pnw = n % 3 - 1;
    float pd = fminf(fmaxf((float)(d + 1 + pnd) + ofd, 0.f), 25.f);
    float ph = fminf(fmaxf((float)(h + 1 + pnh) + ofh, 0.f), 49.f);
    float pw = fminf(fmaxf((float)(w + 1 + pnw) + ofw, 0.f), 65.f);
    int d0 = (int)pd, h0 = (int)ph, w0 = (int)pw;   // >= 0 so trunc == floor
    float fd = pd - d0, fh = ph - h0, fw = pw - w0;
    int d1i = min(d0 + 1, 25), h1i = min(h0 + 1, 49), w1i = min(w0 + 1, 65);
    int zq[2] = {d0, d1i}, yq[2] = {h0, h1i}, xq[2] = {w0, w1i};
    float wz[2] = {1.f - fd, fd}, wy[2] = {1.f - fh, fh}, wx[2] = {1.f - fw, fw};
    float s = 0.f;
    #pragma unroll
    for (int zi = 0; zi < 2; ++zi) {
      float wzv = (zq[zi] >= 1 && zq[zi] <= 24) ? wz[zi] : 0.f;
      int iz = min(max(zq[zi] - 1, 0), 23);
      #pragma unroll
      for (int yi = 0; yi < 2; ++yi) {
        float wyv = (yq[yi] >= 1 && yq[yi] <= 48) ? wy[yi] : 0.f;
        int iy = min(max(yq[yi] - 1, 0), 47);
        #pragma unroll
        for (int xi = 0; xi < 2; ++xi) {
          float wxv = (xq[xi] >= 1 && xq[xi] <= 64) ? wx[xi] : 0.f;
          int ix = min(max(xq[xi] - 1, 0), 63);
          s += wzv * wyv * wxv * xb[(iz * 48 + iy) * 64 + ix];
        }
      }
    }
    const float* w1r = &s_w1t[n * 32];
    #pragma unroll
    for (int o = 0; o < 32; ++o) acc[o] += w1r[o] * s;
  }
  const int sp = (d * 48 + h) * 64 + w;
  #pragma unroll
  for (int o = 0; o < 32; ++o)
    y1[(size_t)(b * 32 + o) * (24 * 48 * 64) + sp] = acc[o] + s_b1[o];
}

// ---------------- BN stats: per-channel sum / sumsq (double atomics) ----------------
__global__ __launch_bounds__(256) void k_stats(const float* __restrict__ v, double* __restrict__ st, int C, int sp)
{
  const int c = blockIdx.x, b = blockIdx.y;
  const float* __restrict__ p = v + (size_t)(b * C + c) * sp;
  double s = 0.0, q = 0.0;
  for (int i = threadIdx.x; i < sp; i += 256) {
    float t = p[i];
    s += t;
    q += (double)t * (double)t;
  }
  #pragma unroll
  for (int o = 32; o > 0; o >>= 1) { s += __shfl_down(s, o); q += __shfl_down(q, o); }
  __shared__ double ls[4], lq[4];
  const int wv = threadIdx.x >> 6;
  if ((threadIdx.x & 63) == 0) { ls[wv] = s; lq[wv] = q; }
  __syncthreads();
  if (threadIdx.x == 0) {
    s = ls[0] + ls[1] + ls[2] + ls[3];
    q = lq[0] + lq[1] + lq[2] + lq[3];
    atomicAdd(&st[c], s);
    atomicAdd(&st[C + c], q);
  }
}

// ---------------- BN apply + ELU + 2x2x2 maxpool ----------------
__global__ __launch_bounds__(256) void k_bnpool(const float* __restrict__ v, const double* __restrict__ st,
    const float* __restrict__ g, const float* __restrict__ be, float* __restrict__ outp,
    int C, int D, int H, int Wd, double inv)
{
  const int gid = blockIdx.x * 256 + threadIdx.x;
  const int W2 = Wd >> 1, H2 = H >> 1, D2 = D >> 1;
  int r = gid;
  const int w2 = r % W2; r /= W2;
  const int h2 = r % H2; r /= H2;
  const int d2 = r % D2; r /= D2;
  const int c = r % C; const int b = r / C;
  const double mean = st[c] * inv;
  double var = st[C + c] * inv - mean * mean;
  if (var < 0.0) var = 0.0;
  const float scale = g[c] / sqrtf((float)var + 1e-5f);
  const float shift = be[c] - (float)mean * scale;
  const float* __restrict__ p = v + ((size_t)(b * C + c) * D + d2 * 2) * H * Wd;
  float m = -3.4e38f;
  #pragma unroll
  for (int i = 0; i < 2; ++i)
    #pragma unroll
    for (int j = 0; j < 2; ++j)
      #pragma unroll
      for (int k = 0; k < 2; ++k) {
        float t = p[(i * H + h2 * 2 + j) * Wd + w2 * 2 + k];
        m = fmaxf(m, eluf(t * scale + shift));
      }
  outp[gid] = m;
}

// ---------------- BN apply + ELU (elementwise) ----------------
__global__ __launch_bounds__(256) void k_bnapply(const float* __restrict__ v, const double* __restrict__ st,
    const float* __restrict__ g, const float* __restrict__ be, float* __restrict__ outp,
    int C, int sp, double inv)
{
  const int gid = blockIdx.x * 256 + threadIdx.x;
  const int c = (gid / sp) % C;
  const double mean = st[c] * inv;
  double var = st[C + c] * inv - mean * mean;
  if (var < 0.0) var = 0.0;
  const float scale = g[c] / sqrtf((float)var + 1e-5f);
  const float shift = be[c] - (float)mean * scale;
  outp[gid] = eluf(v[gid] * scale + shift);
}

// ---------------- stage 2: offset conv (C=32 -> 81), LDS-tiled direct conv ----------------
__global__ __launch_bounds__(256) void k_convoff2(const float* __restrict__ p1, const float* __restrict__ wf,
    const float* __restrict__ bf, float* __restrict__ off2)
{
  __shared__ float patch[8 * 9 * 34];   // 2448 floats: 8 channels x 3x3 x padded row 34
  __shared__ float wsl[32 * 216];       // 6912 floats: 32 oc x (8c x 27 taps)
  const int h = blockIdx.x, d = blockIdx.y, b = blockIdx.z;
  const int tid = threadIdx.x;
  const int w = tid & 31, og = tid >> 5;  // 32 w-lanes x 8 groups; each group owns 4 oc per chunk
  float acc[3][4];
  #pragma unroll
  for (int k = 0; k < 3; ++k)
    #pragma unroll
    for (int j = 0; j < 4; ++j) acc[k][j] = 0.f;

  #pragma unroll 1
  for (int cq = 0; cq < 4; ++cq) {   // channel quarters (8 each)
    __syncthreads();
    for (int i = tid; i < 2448; i += 256) {
      int wx = i % 34; int rr = i / 34;
      int hy = rr % 3; rr /= 3;
      int dz = rr % 3; int cl = rr / 3;
      int c = cq * 8 + cl;
      int zd = d + dz - 1, yh = h + hy - 1, xw = wx - 1;
      bool ok = (unsigned)zd < 12u && (unsigned)yh < 24u && (unsigned)xw < 32u;
      patch[i] = ok ? p1[((size_t)(b * 32 + c) * 12 + zd) * 768 + yh * 32 + xw] : 0.f;
    }
    #pragma unroll
    for (int k = 0; k < 3; ++k) {   // oc chunks of 32 (81 -> 96 padded)
      __syncthreads();
      for (int i = tid; i < 6912; i += 256) {
        int ocl = i / 216, mp = i % 216;
        int oc = k * 32 + ocl;
        wsl[i] = (oc < 81) ? wf[oc * 864 + cq * 216 + mp] : 0.f;
      }
      __syncthreads();
      #pragma unroll 1
      for (int cl = 0; cl < 8; ++cl) {
        #pragma unroll
        for (int kd = 0; kd < 3; ++kd)
          #pragma unroll
          for (int kh = 0; kh < 3; ++kh) {
            const int row = (cl * 3 + kd) * 3 + kh;
            const float p0 = patch[row * 34 + w];
            const float p1v = patch[row * 34 + w + 1];
            const float p2 = patch[row * 34 + w + 2];
            #pragma unroll
            for (int j = 0; j < 4; ++j) {
              const float* wr = &wsl[(og * 4 + j) * 216 + row * 3];
              acc[k][j] += wr[0] * p0 + wr[1] * p1v + wr[2] * p2;
            }
          }
      }
    }
  }
  const int spo = (d * 24 + h) * 32 + w;
  #pragma unroll
  for (int k = 0; k < 3; ++k)
    #pragma unroll
    for (int j = 0; j < 4; ++j) {
      int oc = k * 32 + og * 4 + j;
      if (oc < 81) off2[(size_t)(b * 81 + oc) * 9216 + spo] = acc[k][j] + bf[oc];
    }
}

// ---------------- w2 transpose to [n][c][o] for conflict-free LDS staging ----------------
__global__ __launch_bounds__(256) void k_w2t(const float* __restrict__ w2, float* __restrict__ w2t)
{
  const int i = blockIdx.x * 256 + threadIdx.x;   // 55296 exact
  const int o = i & 63, c = (i >> 6) & 31, n = i >> 11;
  w2t[i] = w2[(o * 32 + c) * 27 + n];
}

// ---------------- stage 2: deformable conv (C=32 -> 64), cooperative sample + tile GEMM ----------------
__global__ __launch_bounds__(256) void k_deform2(
    const float* __restrict__ p1, const float* __restrict__ off2,
    const float* __restrict__ w2t, const float* __restrict__ b2, float* __restrict__ y2)
{
  __shared__ float ss[32 * 64];   // [c][vox]
  __shared__ float sw[32 * 64];   // [c][o]
  const int hb = blockIdx.x, d = blockIdx.y, b = blockIdx.z;
  const int tid = threadIdx.x;
  // sampling role: 64 voxels (2 h-rows x 32 w) x 4 channel groups of 8
  const int vox = tid & 63, cg = tid >> 6;
  const int hl = vox >> 5, w = vox & 31;
  const int h = hb * 2 + hl;
  // GEMM role: 16x16 thread grid over (64 o) x (64 vox), 4x4 register tile
  const int tor = tid >> 4, tvc = tid & 15;
  float acc[4][4];
  #pragma unroll
  for (int i = 0; i < 4; ++i)
    #pragma unroll
    for (int j = 0; j < 4; ++j) acc[i][j] = 0.f;
  const float* __restrict__ pb = p1 + (size_t)b * (32 * 9216);
  const int obase = b * 81 * 9216 + (d * 24 + h) * 32 + w;

  #pragma unroll 1
  for (int n = 0; n < 27; ++n) {
    __syncthreads();
    for (int i = tid; i < 2048; i += 256) sw[i] = w2t[n * 2048 + i];
    float ofd = off2[obase + n * 9216];
    float ofh = off2[obase + (27 + n) * 9216];
    float ofw = off2[obase + (54 + n) * 9216];
    const int pnd = n / 9 - 1, pnh = (n / 3) % 3 - 1, pnw = n % 3 - 1;
    float pd = fminf(fmaxf((float)(d + 1 + pnd) + ofd, 0.f), 13.f);
    float ph = fminf(fmaxf((float)(h + 1 + pnh) + ofh, 0.f), 25.f);
    float pw = fminf(fmaxf((float)(w + 1 + pnw) + ofw, 0.f), 33.f);
    int d0 = (int)pd, h0 = (int)ph, w0 = (int)pw;
    float fd = pd - d0, fh = ph - h0, fw = pw - w0;
    int d1i = min(d0 + 1, 13), h1i = min(h0 + 1, 25), w1i = min(w0 + 1, 33);
    int zq[2] = {d0, d1i}, yq[2] = {h0, h1i}, xq[2] = {w0, w1i};
    float wz[2] = {1.f - fd, fd}, wy[2] = {1.f - fh, fh}, wx[2] = {1.f - fw, fw};
    int ofs[8]; float wgt[8];
    #pragma unroll
    for (int zi = 0; zi < 2; ++zi) {
      float wzv = (zq[zi] >= 1 && zq[zi] <= 12) ? wz[zi] : 0.f;
      int iz = min(max(zq[zi] - 1, 0), 11);
      #pragma unroll
      for (int yi = 0; yi < 2; ++yi) {
        float wyv = (yq[yi] >= 1 && yq[yi] <= 24) ? wy[yi] : 0.f;
        int iy = min(max(yq[yi] - 1, 0), 23);
        #pragma unroll
        for (int xi = 0; xi < 2; ++xi) {
          float wxv = (xq[xi] >= 1 && xq[xi] <= 32) ? wx[xi] : 0.f;
          int ix = min(max(xq[xi] - 1, 0), 31);
          int k = (zi * 2 + yi) * 2 + xi;
          ofs[k] = (iz * 24 + iy) * 32 + ix;
          wgt[k] = wzv * wyv * wxv;
        }
      }
    }
    #pragma unroll
    for (int cc = 0; cc < 8; ++cc) {
      const int c = cg * 8 + cc;
      const float* __restrict__ pc = pb + c * 9216;
      float s = wgt[0] * pc[ofs[0]] + wgt[1] * pc[ofs[1]] + wgt[2] * pc[ofs[2]] + wgt[3] * pc[ofs[3]]
              + wgt[4] * pc[ofs[4]] + wgt[5] * pc[ofs[5]] + wgt[6] * pc[ofs[6]] + wgt[7] * pc[ofs[7]];
      ss[c * 64 + vox] = s;
    }
    __syncthreads();
    #pragma unroll
    for (int c = 0; c < 32; ++c) {
      const float4 wv = *(const float4*)&sw[c * 64 + tor * 4];
      const float4 sv = *(const float4*)&ss[c * 64 + tvc * 4];
      acc[0][0] += wv.x * sv.x; acc[0][1] += wv.x * sv.y; acc[0][2] += wv.x * sv.z; acc[0][3] += wv.x * sv.w;
      acc[1][0] += wv.y * sv.x; acc[1][1] += wv.y * sv.y; acc[1][2] += wv.y * sv.z; acc[1][3] += wv.y * sv.w;
      acc[2][0] += wv.z * sv.x; acc[2][1] += wv.z * sv.y; acc[2][2] += wv.z * sv.z; acc[2][3] += wv.z * sv.w;
      acc[3][0] += wv.w * sv.x; acc[3][1] += wv.w * sv.y; acc[3][2] += wv.w * sv.z; acc[3][3] += wv.w * sv.w;
    }
  }
  #pragma unroll
  for (int i = 0; i < 4; ++i) {
    const int o = tor * 4 + i;
    const float bias = b2[o];
    #pragma unroll
    for (int j = 0; j < 4; ++j) {
      const int v = tvc * 4 + j;
      const int hh = hb * 2 + (v >> 5), ww = v & 31;
      y2[(size_t)(b * 64 + o) * 9216 + (d * 24 + hh) * 32 + ww] = acc[i][j] + bias;
    }
  }
}

// ---------------- classifier head: 2x2x2 mean-pool of codes + FC(9216 -> 2) ----------------
__global__ __launch_bounds__(256) void k_classes(const float* __restrict__ codes, const float* __restrict__ wfc,
    const float* __restrict__ bfc, float* __restrict__ outp)
{
  const int b = blockIdx.x;
  float a0 = 0.f, a1 = 0.f;
  for (int idx = threadIdx.x; idx < 9216; idx += 256) {
    const int xq = idx & 7;
    int r = idx >> 3;
    const int yq = r % 6; r /= 6;
    const int zq = r % 3; const int c = r / 3;
    const float* __restrict__ cb = codes + ((size_t)(b * 64 + c) * 6 + zq * 2) * 192 + yq * 2 * 16 + xq * 2;
    float s = 0.f;
    #pragma unroll
    for (int i = 0; i < 2; ++i)
      #pragma unroll
      for (int j = 0; j < 2; ++j)
        #pragma unroll
        for (int k = 0; k < 2; ++k)
          s += cb[i * 192 + j * 16 + k];
    s *= 0.125f;
    a0 += s * wfc[idx];
    a1 += s * wfc[9216 + idx];
  }
  #pragma unroll
  for (int o = 32; o > 0; o >>= 1) { a0 += __shfl_down(a0, o); a1 += __shfl_down(a1, o); }
  __shared__ float r0[4], r1[4];
  const int wv = threadIdx.x >> 6;
  if ((threadIdx.x & 63) == 0) { r0[wv] = a0; r1[wv] = a1; }
  __syncthreads();
  if (threadIdx.x == 0) {
    outp[b * 2 + 0] = r0[0] + r0[1] + r0[2] + r0[3] + bfc[0];
    outp[b * 2 + 1] = r1[0] + r1[1] + r1[2] + r1[3] + bfc[1];
  }
}

// ---------------- transpose conv 1: codes (64ch, 6x12x16) -> (32ch, 12x24x32) ----------------
__global__ __launch_bounds__(256) void k_convT1(const float* __restrict__ codes, const float* __restrict__ wt1,
    const float* __restrict__ bt1, float* __restrict__ outp)
{
  __shared__ float swt[64 * 8];
  const int gid = blockIdx.x * 256 + threadIdx.x;
  int r = gid;
  const int w = r & 31; r >>= 5;
  const int h = r % 24; r /= 24;
  const int d = r % 12; r /= 12;
  const int o = r & 31; const int b = r >> 5;   // all threads in a block share o
  for (int i = threadIdx.x; i < 512; i += 256) {
    int c = i >> 3, ijk = i & 7;
    swt[i] = wt1[(c * 32 + o) * 8 + ijk];
  }
  __syncthreads();
  const int i0 = (d & 1) * 4 + (h & 1) * 2 + (w & 1);
  const float* __restrict__ cb = codes + (size_t)b * 64 * 1152 + (d >> 1) * 192 + (h >> 1) * 16 + (w >> 1);
  float a = bt1[o];
  #pragma unroll
  for (int c = 0; c < 64; ++c) a += swt[c * 8 + i0] * cb[c * 1152];
  outp[gid] = a;
}

// ---------------- transpose conv 2: (32ch, 12x24x32) -> (1ch, 24x48x64) ----------------
__global__ __launch_bounds__(256) void k_convT2(const float* __restrict__ d1, const float* __restrict__ wt2,
    const float* __restrict__ bt2, float* __restrict__ outp)
{
  __shared__ float swt[256];
  for (int i = threadIdx.x; i < 256; i += 256) swt[i] = wt2[i];
  __syncthreads();
  const int gid = blockIdx.x * 256 + threadIdx.x;
  int r = gid;
  const int w = r & 63; r >>= 6;
  const int h = r % 48; r /= 48;
  const int d = r % 24; const int b = r / 24;
  const int i0 = (d & 1) * 4 + (h & 1) * 2 + (w & 1);
  const float* __restrict__ db = d1 + (size_t)b * 32 * 9216 + (d >> 1) * 768 + (h >> 1) * 32 + (w >> 1);
  float a = bt2[0];
  #pragma unroll
  for (int c = 0; c < 32; ++c) a += swt[c * 8 + i0] * db[c * 9216];
  outp[gid] = a;
}

extern "C" void kernel_launch(void* const* d_in, const int* in_sizes, int n_in,
                              void* d_out, int out_size, void* d_ws, size_t ws_size,
                              hipStream_t stream) {
  const float* x     = (const float*)d_in[0];
  const float* woff1 = (const float*)d_in[1];
  const float* boff1 = (const float*)d_in[2];
  const float* w1    = (const float*)d_in[3];
  const float* b1    = (const float*)d_in[4];
  const float* g1    = (const float*)d_in[5];
  const float* be1   = (const float*)d_in[6];
  const float* woff2 = (const float*)d_in[7];
  const float* boff2 = (const float*)d_in[8];
  const float* w2    = (const float*)d_in[9];
  const float* b2    = (const float*)d_in[10];
  const float* g2    = (const float*)d_in[11];
  const float* be2   = (const float*)d_in[12];
  const float* wt1   = (const float*)d_in[13];
  const float* bt1   = (const float*)d_in[14];
  const float* g3    = (const float*)d_in[15];
  const float* be3   = (const float*)d_in[16];
  const float* wt2   = (const float*)d_in[17];
  const float* bt2   = (const float*)d_in[18];
  const float* g4    = (const float*)d_in[19];
  const float* be4   = (const float*)d_in[20];
  const float* wfc   = (const float*)d_in[21];
  const float* bfc   = (const float*)d_in[22];
  float* out = (float*)d_out;

  char* Wb = (char*)d_ws;
  double* st1 = (double*)(Wb);            // 32*2 doubles
  double* st2 = (double*)(Wb + 512);      // 64*2 doubles
  double* st3 = (double*)(Wb + 1536);     // 32*2 doubles
  double* st4 = (double*)(Wb + 2048);     // 1*2 doubles
  float* w2t  = (float*)(Wb + 4096);                       // 55296 f
  float* p1   = (float*)(Wb + 225280);                     // 2359296 f
  float* y1   = (float*)(Wb + 9662464);                    // 18874368 f (dead after BN1 pool)
  float* off2 = (float*)(Wb + 9662464);                    // aliases y1 (5971968 f)
  float* y2   = (float*)(Wb + 9662464 + 23887872);         // 4718592 f
  float* d1b  = (float*)(Wb + 9662464 + 42762240);         // 2359296 f
  float* d2b  = (float*)(Wb + 9662464 + 52199424);         // 589824 f
  float* codes = out;                // 589824 f
  float* dec   = out + 589824;       // 589824 f
  float* cls   = out + 1179648;      // 16 f

  hipMemsetAsync(d_ws, 0, 4096, stream);   // zero BN stats
  k_w2t<<<216, 256, 0, stream>>>(w2, w2t);
  k_deform1<<<2304, 256, 0, stream>>>(x, woff1, boff1, w1, b1, y1);
  k_stats<<<dim3(32, 8), 256, 0, stream>>>(y1, st1, 32, 73728);
  k_bnpool<<<9216, 256, 0, stream>>>(y1, st1, g1, be1, p1, 32, 24, 48, 64, 1.0 / 589824.0);
  k_convoff2<<<dim3(24, 12, 8), 256, 0, stream>>>(p1, woff2, boff2, off2);
  k_deform2<<<dim3(12, 12, 8), 256, 0, stream>>>(p1, off2, w2t, b2, y2);
  k_stats<<<dim3(64, 8), 256, 0, stream>>>(y2, st2, 64, 9216);
  k_bnpool<<<2304, 256, 0, stream>>>(y2, st2, g2, be2, codes, 64, 12, 24, 32, 1.0 / 73728.0);
  k_classes<<<8, 256, 0, stream>>>(codes, wfc, bfc, cls);
  k_convT1<<<9216, 256, 0, stream>>>(codes, wt1, bt1, d1b);
  k_stats<<<dim3(32, 8), 256, 0, stream>>>(d1b, st3, 32, 9216);
  k_bnapply<<<9216, 256, 0, stream>>>(d1b, st3, g3, be3, d1b, 32, 9216, 1.0 / 73728.0);
  k_convT2<<<2304, 256, 0, stream>>>(d1b, wt2, bt2, d2b);
  k_stats<<<dim3(1, 8), 256, 0, stream>>>(d2b, st4, 1, 73728);
  k_bnapply<<<2304, 256, 0, stream>>>(d2b, st4, g4, be4, dec, 1, 73728, 1.0 / 589824.0);
}

// Round 9
// 1263.993 us; speedup vs baseline: 1.0822x; 1.0822x over previous
//
#include <hip/hip_runtime.h>
#include <cmath>

static __device__ __forceinline__ float eluf(float v) { return v > 0.f ? v : expm1f(v); }

// ---------------- stage 1: fused offset-conv + deformable conv (C=1 -> 32) ----------------
__global__ __launch_bounds__(256) void k_deform1(
    const float* __restrict__ x, const float* __restrict__ woff, const float* __restrict__ boff,
    const float* __restrict__ w1, const float* __restrict__ b1, float* __restrict__ y1)
{
  __shared__ float s_woff[81 * 28];   // rows padded to 28 for 16B alignment
  __shared__ float s_w1t[27 * 32];    // [n][o]
  __shared__ float s_boff[81];
  __shared__ float s_b1[32];
  const int tid = threadIdx.x;
  for (int i = tid; i < 81 * 28; i += 256) {
    int ch = i / 28, m = i % 28;
    s_woff[i] = (m < 27) ? woff[ch * 27 + m] : 0.f;
  }
  for (int i = tid; i < 27 * 32; i += 256) {
    int n = i >> 5, o = i & 31;
    s_w1t[i] = w1[o * 27 + n];
  }
  if (tid < 81) s_boff[tid] = boff[tid];
  if (tid < 32) s_b1[tid] = b1[tid];
  __syncthreads();

  const int gid = blockIdx.x * 256 + tid;
  const int w = gid & 63;
  const int h = (gid >> 6) % 48;
  const int d = ((gid >> 6) / 48) % 24;
  const int b = gid / (64 * 48 * 24);
  const float* __restrict__ xb = x + (size_t)b * (24 * 48 * 64);

  float xn[27];
  #pragma unroll
  for (int kd = 0; kd < 3; ++kd)
    #pragma unroll
    for (int kh = 0; kh < 3; ++kh)
      #pragma unroll
      for (int kw = 0; kw < 3; ++kw) {
        int zd = d + kd - 1, yh = h + kh - 1, xw = w + kw - 1;
        bool ok = (unsigned)zd < 24u && (unsigned)yh < 48u && (unsigned)xw < 64u;
        xn[(kd * 3 + kh) * 3 + kw] = ok ? xb[(zd * 48 + yh) * 64 + xw] : 0.f;
      }

  float acc[32];
  #pragma unroll
  for (int o = 0; o < 32; ++o) acc[o] = 0.f;

  #pragma unroll 1
  for (int n = 0; n < 27; ++n) {
    const float* wrd = &s_woff[n * 28];
    const float* wrh = &s_woff[(27 + n) * 28];
    const float* wrw = &s_woff[(54 + n) * 28];
    float ofd = s_boff[n], ofh = s_boff[27 + n], ofw = s_boff[54 + n];
    #pragma unroll
    for (int m = 0; m < 27; ++m) {
      float xv = xn[m];
      ofd += wrd[m] * xv; ofh += wrh[m] * xv; ofw += wrw[m] * xv;
    }
    const int pnd = n / 9 - 1, pnh = (n / 3) % 3 - 1, pnw = n % 3 - 1;
    float pd = fminf(fmaxf((float)(d + 1 + pnd) + ofd, 0.f), 25.f);
    float ph = fminf(fmaxf((float)(h + 1 + pnh) + ofh, 0.f), 49.f);
    float pw = fminf(fmaxf((float)(w + 1 + pnw) + ofw, 0.f), 65.f);
    int d0 = (int)pd, h0 = (int)ph, w0 = (int)pw;   // >= 0 so trunc == floor
    float fd = pd - d0, fh = ph - h0, fw = pw - w0;
    int d1i = min(d0 + 1, 25), h1i = min(h0 + 1, 49), w1i = min(w0 + 1, 65);
    int zq[2] = {d0, d1i}, yq[2] = {h0, h1i}, xq[2] = {w0, w1i};
    float wz[2] = {1.f - fd, fd}, wy[2] = {1.f - fh, fh}, wx[2] = {1.f - fw, fw};
    float s = 0.f;
    #pragma unroll
    for (int zi = 0; zi < 2; ++zi) {
      float wzv = (zq[zi] >= 1 && zq[zi] <= 24) ? wz[zi] : 0.f;
      int iz = min(max(zq[zi] - 1, 0), 23);
      #pragma unroll
      for (int yi = 0; yi < 2; ++yi) {
        float wyv = (yq[yi] >= 1 && yq[yi] <= 48) ? wy[yi] : 0.f;
        int iy = min(max(yq[yi] - 1, 0), 47);
        #pragma unroll
        for (int xi = 0; xi < 2; ++xi) {
          float wxv = (xq[xi] >= 1 && xq[xi] <= 64) ? wx[xi] : 0.f;
          int ix = min(max(xq[xi] - 1, 0), 63);
          s += wzv * wyv * wxv * xb[(iz * 48 + iy) * 64 + ix];
        }
      }
    }
    const float* w1r = &s_w1t[n * 32];
    #pragma unroll
    for (int o = 0; o < 32; ++o) acc[o] += w1r[o] * s;
  }
  const int sp = (d * 48 + h) * 64 + w;
  #pragma unroll
  for (int o = 0; o < 32; ++o)
    y1[(size_t)(b * 32 + o) * (24 * 48 * 64) + sp] = acc[o] + s_b1[o];
}

// ---------------- BN stats: per-channel sum / sumsq (double atomics) ----------------
__global__ __launch_bounds__(256) void k_stats(const float* __restrict__ v, double* __restrict__ st, int C, int sp)
{
  const int c = blockIdx.x, b = blockIdx.y;
  const float* __restrict__ p = v + (size_t)(b * C + c) * sp;
  double s = 0.0, q = 0.0;
  for (int i = threadIdx.x; i < sp; i += 256) {
    float t = p[i];
    s += t;
    q += (double)t * (double)t;
  }
  #pragma unroll
  for (int o = 32; o > 0; o >>= 1) { s += __shfl_down(s, o); q += __shfl_down(q, o); }
  __shared__ double ls[4], lq[4];
  const int wv = threadIdx.x >> 6;
  if ((threadIdx.x & 63) == 0) { ls[wv] = s; lq[wv] = q; }
  __syncthreads();
  if (threadIdx.x == 0) {
    s = ls[0] + ls[1] + ls[2] + ls[3];
    q = lq[0] + lq[1] + lq[2] + lq[3];
    atomicAdd(&st[c], s);
    atomicAdd(&st[C + c], q);
  }
}

// ---------------- BN apply + ELU + 2x2x2 maxpool ----------------
__global__ __launch_bounds__(256) void k_bnpool(const float* __restrict__ v, const double* __restrict__ st,
    const float* __restrict__ g, const float* __restrict__ be, float* __restrict__ outp,
    int C, int D, int H, int Wd, double inv)
{
  const int gid = blockIdx.x * 256 + threadIdx.x;
  const int W2 = Wd >> 1, H2 = H >> 1, D2 = D >> 1;
  int r = gid;
  const int w2 = r % W2; r /= W2;
  const int h2 = r % H2; r /= H2;
  const int d2 = r % D2; r /= D2;
  const int c = r % C; const int b = r / C;
  const double mean = st[c] * inv;
  double var = st[C + c] * inv - mean * mean;
  if (var < 0.0) var = 0.0;
  const float scale = g[c] / sqrtf((float)var + 1e-5f);
  const float shift = be[c] - (float)mean * scale;
  const float* __restrict__ p = v + ((size_t)(b * C + c) * D + d2 * 2) * H * Wd;
  float m = -3.4e38f;
  #pragma unroll
  for (int i = 0; i < 2; ++i)
    #pragma unroll
    for (int j = 0; j < 2; ++j)
      #pragma unroll
      for (int k = 0; k < 2; ++k) {
        float t = p[(i * H + h2 * 2 + j) * Wd + w2 * 2 + k];
        m = fmaxf(m, eluf(t * scale + shift));
      }
  outp[gid] = m;
}

// ---------------- BN apply + ELU (elementwise) ----------------
__global__ __launch_bounds__(256) void k_bnapply(const float* __restrict__ v, const double* __restrict__ st,
    const float* __restrict__ g, const float* __restrict__ be, float* __restrict__ outp,
    int C, int sp, double inv)
{
  const int gid = blockIdx.x * 256 + threadIdx.x;
  const int c = (gid / sp) % C;
  const double mean = st[c] * inv;
  double var = st[C + c] * inv - mean * mean;
  if (var < 0.0) var = 0.0;
  const float scale = g[c] / sqrtf((float)var + 1e-5f);
  const float shift = be[c] - (float)mean * scale;
  outp[gid] = eluf(v[gid] * scale + shift);
}

// ---------------- stage 2: offset conv (C=32 -> 81), LDS-tiled direct conv ----------------
// Round-4 passing structure; delta: wsl layout transposed to [tap][oc_l] so the
// per-tap weight fetch is one aligned float4 across 4 oc (6 LDS ops / 12 FMAs vs 15).
__global__ __launch_bounds__(256) void k_convoff2(const float* __restrict__ p1, const float* __restrict__ wf,
    const float* __restrict__ bf, float* __restrict__ off2)
{
  __shared__ float patch[8 * 9 * 34];   // 2448 floats: 8 channels x 3x3 x padded row 34
  __shared__ float wsl[216 * 32];       // 6912 floats: [tap m][oc_l], m = cl*27+kd*9+kh*3+kw
  const int h = blockIdx.x, d = blockIdx.y, b = blockIdx.z;
  const int tid = threadIdx.x;
  const int w = tid & 31, og = tid >> 5;  // 32 w-lanes x 8 groups; each group owns 4 oc per chunk
  float acc[3][4];
  #pragma unroll
  for (int k = 0; k < 3; ++k)
    #pragma unroll
    for (int j = 0; j < 4; ++j) acc[k][j] = 0.f;

  #pragma unroll 1
  for (int cq = 0; cq < 4; ++cq) {   // channel quarters (8 each)
    __syncthreads();
    for (int i = tid; i < 2448; i += 256) {
      int wx = i % 34; int rr = i / 34;
      int hy = rr % 3; rr /= 3;
      int dz = rr % 3; int cl = rr / 3;
      int c = cq * 8 + cl;
      int zd = d + dz - 1, yh = h + hy - 1, xw = wx - 1;
      bool ok = (unsigned)zd < 12u && (unsigned)yh < 24u && (unsigned)xw < 32u;
      patch[i] = ok ? p1[((size_t)(b * 32 + c) * 12 + zd) * 768 + yh * 32 + xw] : 0.f;
    }
    #pragma unroll
    for (int k = 0; k < 3; ++k) {   // oc chunks of 32 (81 -> 96 padded)
      __syncthreads();
      // wsl[m*32 + ocl] = wf[oc*864 + cq*216 + m]; linear LDS write (i = m*32+ocl),
      // global gather stride-864 across lanes (27.6 KB chunk, L1-resident).
      for (int i = tid; i < 6912; i += 256) {
        int ocl = i & 31, m = i >> 5;
        int oc = k * 32 + ocl;
        wsl[i] = (oc < 81) ? wf[oc * 864 + cq * 216 + m] : 0.f;
      }
      __syncthreads();
      #pragma unroll 1
      for (int cl = 0; cl < 8; ++cl) {
        #pragma unroll
        for (int kd = 0; kd < 3; ++kd)
          #pragma unroll
          for (int kh = 0; kh < 3; ++kh) {
            const int row = (cl * 3 + kd) * 3 + kh;
            const float p0 = patch[row * 34 + w];
            const float p1v = patch[row * 34 + w + 1];
            const float p2 = patch[row * 34 + w + 2];
            const float4 q0 = *(const float4*)&wsl[(row * 3 + 0) * 32 + og * 4];
            const float4 q1 = *(const float4*)&wsl[(row * 3 + 1) * 32 + og * 4];
            const float4 q2 = *(const float4*)&wsl[(row * 3 + 2) * 32 + og * 4];
            acc[k][0] += q0.x * p0 + q1.x * p1v + q2.x * p2;
            acc[k][1] += q0.y * p0 + q1.y * p1v + q2.y * p2;
            acc[k][2] += q0.z * p0 + q1.z * p1v + q2.z * p2;
            acc[k][3] += q0.w * p0 + q1.w * p1v + q2.w * p2;
          }
      }
    }
  }
  const int spo = (d * 24 + h) * 32 + w;
  #pragma unroll
  for (int k = 0; k < 3; ++k)
    #pragma unroll
    for (int j = 0; j < 4; ++j) {
      int oc = k * 32 + og * 4 + j;
      if (oc < 81) off2[(size_t)(b * 81 + oc) * 9216 + spo] = acc[k][j] + bf[oc];
    }
}

// ---------------- w2 transpose to [n][c][o] for conflict-free LDS staging ----------------
__global__ __launch_bounds__(256) void k_w2t(const float* __restrict__ w2, float* __restrict__ w2t)
{
  const int i = blockIdx.x * 256 + threadIdx.x;   // 55296 exact
  const int o = i & 63, c = (i >> 6) & 31, n = i >> 11;
  w2t[i] = w2[(o * 32 + c) * 27 + n];
}

// ---------------- stage 2: deformable conv (C=32 -> 64), cooperative sample + tile GEMM ----------------
__global__ __launch_bounds__(256) void k_deform2(
    const float* __restrict__ p1, const float* __restrict__ off2,
    const float* __restrict__ w2t, const float* __restrict__ b2, float* __restrict__ y2)
{
  __shared__ float ss[32 * 64];   // [c][vox]
  __shared__ float sw[32 * 64];   // [c][o]
  const int hb = blockIdx.x, d = blockIdx.y, b = blockIdx.z;
  const int tid = threadIdx.x;
  // sampling role: 64 voxels (2 h-rows x 32 w) x 4 channel groups of 8
  const int vox = tid & 63, cg = tid >> 6;
  const int hl = vox >> 5, w = vox & 31;
  const int h = hb * 2 + hl;
  // GEMM role: 16x16 thread grid over (64 o) x (64 vox), 4x4 register tile
  const int tor = tid >> 4, tvc = tid & 15;
  float acc[4][4];
  #pragma unroll
  for (int i = 0; i < 4; ++i)
    #pragma unroll
    for (int j = 0; j < 4; ++j) acc[i][j] = 0.f;
  const float* __restrict__ pb = p1 + (size_t)b * (32 * 9216);
  const int obase = b * 81 * 9216 + (d * 24 + h) * 32 + w;

  #pragma unroll 1
  for (int n = 0; n < 27; ++n) {
    __syncthreads();
    for (int i = tid; i < 2048; i += 256) sw[i] = w2t[n * 2048 + i];
    float ofd = off2[obase + n * 9216];
    float ofh = off2[obase + (27 + n) * 9216];
    float ofw = off2[obase + (54 + n) * 9216];
    const int pnd = n / 9 - 1, pnh = (n / 3) % 3 - 1, pnw = n % 3 - 1;
    float pd = fminf(fmaxf((float)(d + 1 + pnd) + ofd, 0.f), 13.f);
    float ph = fminf(fmaxf((float)(h + 1 + pnh) + ofh, 0.f), 25.f);
    float pw = fminf(fmaxf((float)(w + 1 + pnw) + ofw, 0.f), 33.f);
    int d0 = (int)pd, h0 = (int)ph, w0 = (int)pw;
    float fd = pd - d0, fh = ph - h0, fw = pw - w0;
    int d1i = min(d0 + 1, 13), h1i = min(h0 + 1, 25), w1i = min(w0 + 1, 33);
    int zq[2] = {d0, d1i}, yq[2] = {h0, h1i}, xq[2] = {w0, w1i};
    float wz[2] = {1.f - fd, fd}, wy[2] = {1.f - fh, fh}, wx[2] = {1.f - fw, fw};
    int ofs[8]; float wgt[8];
    #pragma unroll
    for (int zi = 0; zi < 2; ++zi) {
      float wzv = (zq[zi] >= 1 && zq[zi] <= 12) ? wz[zi] : 0.f;
      int iz = min(max(zq[zi] - 1, 0), 11);
      #pragma unroll
      for (int yi = 0; yi < 2; ++yi) {
        float wyv = (yq[yi] >= 1 && yq[yi] <= 24) ? wy[yi] : 0.f;
        int iy = min(max(yq[yi] - 1, 0), 23);
        #pragma unroll
        for (int xi = 0; xi < 2; ++xi) {
          float wxv = (xq[xi] >= 1 && xq[xi] <= 32) ? wx[xi] : 0.f;
          int ix = min(max(xq[xi] - 1, 0), 31);
          int k = (zi * 2 + yi) * 2 + xi;
          ofs[k] = (iz * 24 + iy) * 32 + ix;
          wgt[k] = wzv * wyv * wxv;
        }
      }
    }
    #pragma unroll
    for (int cc = 0; cc < 8; ++cc) {
      const int c = cg * 8 + cc;
      const float* __restrict__ pc = pb + c * 9216;
      float s = wgt[0] * pc[ofs[0]] + wgt[1] * pc[ofs[1]] + wgt[2] * pc[ofs[2]] + wgt[3] * pc[ofs[3]]
              + wgt[4] * pc[ofs[4]] + wgt[5] * pc[ofs[5]] + wgt[6] * pc[ofs[6]] + wgt[7] * pc[ofs[7]];
      ss[c * 64 + vox] = s;
    }
    __syncthreads();
    #pragma unroll
    for (int c = 0; c < 32; ++c) {
      const float4 wv = *(const float4*)&sw[c * 64 + tor * 4];
      const float4 sv = *(const float4*)&ss[c * 64 + tvc * 4];
      acc[0][0] += wv.x * sv.x; acc[0][1] += wv.x * sv.y; acc[0][2] += wv.x * sv.z; acc[0][3] += wv.x * sv.w;
      acc[1][0] += wv.y * sv.x; acc[1][1] += wv.y * sv.y; acc[1][2] += wv.y * sv.z; acc[1][3] += wv.y * sv.w;
      acc[2][0] += wv.z * sv.x; acc[2][1] += wv.z * sv.y; acc[2][2] += wv.z * sv.z; acc[2][3] += wv.z * sv.w;
      acc[3][0] += wv.w * sv.x; acc[3][1] += wv.w * sv.y; acc[3][2] += wv.w * sv.z; acc[3][3] += wv.w * sv.w;
    }
  }
  #pragma unroll
  for (int i = 0; i < 4; ++i) {
    const int o = tor * 4 + i;
    const float bias = b2[o];
    #pragma unroll
    for (int j = 0; j < 4; ++j) {
      const int v = tvc * 4 + j;
      const int hh = hb * 2 + (v >> 5), ww = v & 31;
      y2[(size_t)(b * 64 + o) * 9216 + (d * 24 + hh) * 32 + ww] = acc[i][j] + bias;
    }
  }
}

// ---------------- classifier head: 2x2x2 mean-pool of codes + FC(9216 -> 2) ----------------
__global__ __launch_bounds__(256) void k_classes(const float* __restrict__ codes, const float* __restrict__ wfc,
    const float* __restrict__ bfc, float* __restrict__ outp)
{
  const int b = blockIdx.x;
  float a0 = 0.f, a1 = 0.f;
  for (int idx = threadIdx.x; idx < 9216; idx += 256) {
    const int xq = idx & 7;
    int r = idx >> 3;
    const int yq = r % 6; r /= 6;
    const int zq = r % 3; const int c = r / 3;
    const float* __restrict__ cb = codes + ((size_t)(b * 64 + c) * 6 + zq * 2) * 192 + yq * 2 * 16 + xq * 2;
    float s = 0.f;
    #pragma unroll
    for (int i = 0; i < 2; ++i)
      #pragma unroll
      for (int j = 0; j < 2; ++j)
        #pragma unroll
        for (int k = 0; k < 2; ++k)
          s += cb[i * 192 + j * 16 + k];
    s *= 0.125f;
    a0 += s * wfc[idx];
    a1 += s * wfc[9216 + idx];
  }
  #pragma unroll
  for (int o = 32; o > 0; o >>= 1) { a0 += __shfl_down(a0, o); a1 += __shfl_down(a1, o); }
  __shared__ float r0[4], r1[4];
  const int wv = threadIdx.x >> 6;
  if ((threadIdx.x & 63) == 0) { r0[wv] = a0; r1[wv] = a1; }
  __syncthreads();
  if (threadIdx.x == 0) {
    outp[b * 2 + 0] = r0[0] + r0[1] + r0[2] + r0[3] + bfc[0];
    outp[b * 2 + 1] = r1[0] + r1[1] + r1[2] + r1[3] + bfc[1];
  }
}

// ---------------- transpose conv 1: codes (64ch, 6x12x16) -> (32ch, 12x24x32) ----------------
__global__ __launch_bounds__(256) void k_convT1(const float* __restrict__ codes, const float* __restrict__ wt1,
    const float* __restrict__ bt1, float* __restrict__ outp)
{
  __shared__ float swt[64 * 8];
  const int gid = blockIdx.x * 256 + threadIdx.x;
  int r = gid;
  const int w = r & 31; r >>= 5;
  const int h = r % 24; r /= 24;
  const int d = r % 12; r /= 12;
  const int o = r & 31; const int b = r >> 5;   // all threads in a block share o
  for (int i = threadIdx.x; i < 512; i += 256) {
    int c = i >> 3, ijk = i & 7;
    swt[i] = wt1[(c * 32 + o) * 8 + ijk];
  }
  __syncthreads();
  const int i0 = (d & 1) * 4 + (h & 1) * 2 + (w & 1);
  const float* __restrict__ cb = codes + (size_t)b * 64 * 1152 + (d >> 1) * 192 + (h >> 1) * 16 + (w >> 1);
  float a = bt1[o];
  #pragma unroll
  for (int c = 0; c < 64; ++c) a += swt[c * 8 + i0] * cb[c * 1152];
  outp[gid] = a;
}

// ---------------- transpose conv 2: (32ch, 12x24x32) -> (1ch, 24x48x64) ----------------
__global__ __launch_bounds__(256) void k_convT2(const float* __restrict__ d1, const float* __restrict__ wt2,
    const float* __restrict__ bt2, float* __restrict__ outp)
{
  __shared__ float swt[256];
  for (int i = threadIdx.x; i < 256; i += 256) swt[i] = wt2[i];
  __syncthreads();
  const int gid = blockIdx.x * 256 + threadIdx.x;
  int r = gid;
  const int w = r & 63; r >>= 6;
  const int h = r % 48; r /= 48;
  const int d = r % 24; const int b = r / 24;
  const int i0 = (d & 1) * 4 + (h & 1) * 2 + (w & 1);
  const float* __restrict__ db = d1 + (size_t)b * 32 * 9216 + (d >> 1) * 768 + (h >> 1) * 32 + (w >> 1);
  float a = bt2[0];
  #pragma unroll
  for (int c = 0; c < 32; ++c) a += swt[c * 8 + i0] * db[c * 9216];
  outp[gid] = a;
}

extern "C" void kernel_launch(void* const* d_in, const int* in_sizes, int n_in,
                              void* d_out, int out_size, void* d_ws, size_t ws_size,
                              hipStream_t stream) {
  const float* x     = (const float*)d_in[0];
  const float* woff1 = (const float*)d_in[1];
  const float* boff1 = (const float*)d_in[2];
  const float* w1    = (const float*)d_in[3];
  const float* b1    = (const float*)d_in[4];
  const float* g1    = (const float*)d_in[5];
  const float* be1   = (const float*)d_in[6];
  const float* woff2 = (const float*)d_in[7];
  const float* boff2 = (const float*)d_in[8];
  const float* w2    = (const float*)d_in[9];
  const float* b2    = (const float*)d_in[10];
  const float* g2    = (const float*)d_in[11];
  const float* be2   = (const float*)d_in[12];
  const float* wt1   = (const float*)d_in[13];
  const float* bt1   = (const float*)d_in[14];
  const float* g3    = (const float*)d_in[15];
  const float* be3   = (const float*)d_in[16];
  const float* wt2   = (const float*)d_in[17];
  const float* bt2   = (const float*)d_in[18];
  const float* g4    = (const float*)d_in[19];
  const float* be4   = (const float*)d_in[20];
  const float* wfc   = (const float*)d_in[21];
  const float* bfc   = (const float*)d_in[22];
  float* out = (float*)d_out;

  char* Wb = (char*)d_ws;
  double* st1 = (double*)(Wb);            // 32*2 doubles
  double* st2 = (double*)(Wb + 512);      // 64*2 doubles
  double* st3 = (double*)(Wb + 1536);     // 32*2 doubles
  double* st4 = (double*)(Wb + 2048);     // 1*2 doubles
  float* w2t  = (float*)(Wb + 4096);                       // 55296 f
  float* p1   = (float*)(Wb + 225280);                     // 2359296 f
  float* y1   = (float*)(Wb + 9662464);                    // 18874368 f (dead after BN1 pool)
  float* off2 = (float*)(Wb + 9662464);                    // aliases y1 (5971968 f)
  float* y2   = (float*)(Wb + 9662464 + 23887872);         // 4718592 f
  float* d1b  = (float*)(Wb + 9662464 + 42762240);         // 2359296 f
  float* d2b  = (float*)(Wb + 9662464 + 52199424);         // 589824 f
  float* codes = out;                // 589824 f
  float* dec   = out + 589824;       // 589824 f
  float* cls   = out + 1179648;      // 16 f

  hipMemsetAsync(d_ws, 0, 4096, stream);   // zero BN stats
  k_w2t<<<216, 256, 0, stream>>>(w2, w2t);
  k_deform1<<<2304, 256, 0, stream>>>(x, woff1, boff1, w1, b1, y1);
  k_stats<<<dim3(32, 8), 256, 0, stream>>>(y1, st1, 32, 73728);
  k_bnpool<<<9216, 256, 0, stream>>>(y1, st1, g1, be1, p1, 32, 24, 48, 64, 1.0 / 589824.0);
  k_convoff2<<<dim3(24, 12, 8), 256, 0, stream>>>(p1, woff2, boff2, off2);
  k_deform2<<<dim3(12, 12, 8), 256, 0, stream>>>(p1, off2, w2t, b2, y2);
  k_stats<<<dim3(64, 8), 256, 0, stream>>>(y2, st2, 64, 9216);
  k_bnpool<<<2304, 256, 0, stream>>>(y2, st2, g2, be2, codes, 64, 12, 24, 32, 1.0 / 73728.0);
  k_classes<<<8, 256, 0, stream>>>(codes, wfc, bfc, cls);
  k_convT1<<<9216, 256, 0, stream>>>(codes, wt1, bt1, d1b);
  k_stats<<<dim3(32, 8), 256, 0, stream>>>(d1b, st3, 32, 9216);
  k_bnapply<<<9216, 256, 0, stream>>>(d1b, st3, g3, be3, d1b, 32, 9216, 1.0 / 73728.0);
  k_convT2<<<2304, 256, 0, stream>>>(d1b, wt2, bt2, d2b);
  k_stats<<<dim3(1, 8), 256, 0, stream>>>(d2b, st4, 1, 73728);
  k_bnapply<<<2304, 256, 0, stream>>>(d2b, st4, g4, be4, dec, 1, 73728, 1.0 / 589824.0);
}